// Round 6
// baseline (806.819 us; speedup 1.0000x reference)
//
#include <hip/hip_runtime.h>
#include <math.h>

#define BB 64
#define DD 8732
#define CC 81
#define NN 50
#define GRID_MAIN 2048
#define NWAVES (GRID_MAIN * 4)      // 8192 waves
#define NGROUPS (BB * DD / 4)       // 139712 groups of 4 rows
#define GPB (DD / 4)                // 2183 groups per batch

// conf rows are 324 B apart -> per-row float4 slices are only dword-aligned.
typedef float f4u __attribute__((ext_vector_type(4), aligned(4)));

// ---------------- k_main: match + smooth-L1 + CE + mining, one pass ----------
__global__ __launch_bounds__(256) void k_main(
    const float* __restrict__ loc_data,   // [B,D,4]
    const float* __restrict__ conf_data,  // [B,D,C]
    const float* __restrict__ dboxes,     // [D,4]
    const float* __restrict__ tboxes,     // [B,N,4]
    const int*   __restrict__ tlabels,    // [B,N]
    float* __restrict__ ce_mined,         // [B*D]
    int*   __restrict__ num_pos,          // [B]  (pre-zeroed)
    float* __restrict__ acc)              // [2]  (pre-zeroed)
{
    const int tid  = threadIdx.x;
    const int lane = tid & 63;
    const int q    = lane >> 4;           // quarter = row within group
    const int s    = lane & 15;           // sublane within quarter
    const int gw   = (blockIdx.x * 256 + tid) >> 6;

    float ll = 0.0f, lc = 0.0f;

    for (int g = gw; g < NGROUPS; g += NWAVES) {
        const int b = g / GPB;                    // groups never straddle batches
        const int r = g * 4 + q;                  // global row = b*DD + d
        const int d = (g - b * GPB) * 4 + q;      // prior index

        // conf row: lane s -> cols 4s..4s+3; lanes 0..3 also 64+4s..; lane 4 col 80
        const float* row = conf_data + (size_t)r * CC;
        f4u x4 = *(const f4u*)(row + 4 * s);
        f4u y4 = {0.f, 0.f, 0.f, 0.f};
        float z = 0.f;
        if (s < 4)  y4 = *(const f4u*)(row + 64 + 4 * s);
        if (s == 4) z = row[80];

        // ---- match: 4 gt boxes per lane, global first-max across 16 lanes
        const float4 db = ((const float4*)dboxes)[d];
        const float dA = (db.x - db.z) * (db.y - db.w);
        float bI = -1.0f; int bN = 0;
        #pragma unroll
        for (int j = 0; j < 4; j++) {
            const int n = s + 16 * j;
            if (n < NN) {
                const float4 tb = ((const float4*)tboxes)[b * NN + n];
                float lx = fmaxf(tb.x, db.x), ly = fmaxf(tb.y, db.y);
                float rx = fminf(tb.z, db.z), ry = fminf(tb.w, db.w);
                float w = fmaxf(rx - lx, 0.f), h = fmaxf(ry - ly, 0.f);
                float inter = w * h;
                float tA = (tb.x - tb.z) * (tb.y - tb.w);
                float iou = inter / (tA + dA - inter);
                if (iou > bI) { bI = iou; bN = n; }   // ascending n, strict >
            }
        }
        #pragma unroll
        for (int off = 1; off < 16; off <<= 1) {      // tie -> smaller idx (first-max)
            float oI = __shfl_xor(bI, off);
            int   oN = __shfl_xor(bN, off);
            if (oI > bI || (oI == bI && oN < bN)) { bI = oI; bN = oN; }
        }
        const int lbl = tlabels[b * NN + bN];
        const int ct  = (bI < 0.5f) ? 0 : (lbl + 1);
        const bool pos = (ct > 0);

        // ---- CE: exp-sum (logits ~N(0,1): direct fp32 exp-sum is safe)
        float e = __expf(x4.x) + __expf(x4.y) + __expf(x4.z) + __expf(x4.w);
        if (s < 4)  e += __expf(y4.x) + __expf(y4.y) + __expf(y4.z) + __expf(y4.w);
        if (s == 4) e += __expf(z);
        float v = 0.f;                                // x[ct] contribution
        if (ct < 64) {
            if (s == (ct >> 2)) {
                int e3 = ct & 3;
                v = (e3 == 0) ? x4.x : (e3 == 1) ? x4.y : (e3 == 2) ? x4.z : x4.w;
            }
        } else if (ct < 80) {
            if (s == ((ct - 64) >> 2)) {
                int e3 = (ct - 64) & 3;
                v = (e3 == 0) ? y4.x : (e3 == 1) ? y4.y : (e3 == 2) ? y4.z : y4.w;
            }
        } else {
            if (s == 4) v = z;
        }
        #pragma unroll
        for (int off = 1; off < 16; off <<= 1) {
            e += __shfl_xor(e, off);
            v += __shfl_xor(v, off);
        }

        if (s == 0) {
            float ce = fmaxf(__logf(e) - v, 0.0f);
            ce_mined[r] = pos ? 0.0f : ce;
            if (pos) {
                lc += ce;
                const float4 bb  = ((const float4*)tboxes)[b * NN + bN];
                const float4 ldv = ((const float4*)loc_data)[r];
                float dw = db.z - db.x, dh = db.w - db.y;
                float t0 = ((bb.x - db.x) + (bb.z - db.z)) * 0.5f * 10.0f / dw;
                float t1 = ((bb.y - db.y) + (bb.w - db.w)) * 0.5f * 10.0f / dh;
                float t2 = __logf((bb.z - bb.x) / dw) * 5.0f;
                float t3 = __logf((bb.w - bb.y) / dh) * 5.0f;
                float xs[4] = {ldv.x - t0, ldv.y - t1, ldv.z - t2, ldv.w - t3};
                #pragma unroll
                for (int k = 0; k < 4; k++) {
                    float ax = fabsf(xs[k]);
                    ll += (ax < 1.0f) ? 0.5f * xs[k] * xs[k] : ax - 0.5f;
                }
            }
        }
        unsigned long long bal = __ballot(s == 0 && pos);  // wave's 4 rows share b
        if (lane == 0) {
            int c = (int)__popcll(bal);
            if (c) atomicAdd(&num_pos[b], c);
        }
    }
    // fold per-wave partials (live on lanes 0,16,32,48; others are 0)
    #pragma unroll
    for (int off = 32; off > 0; off >>= 1) {
        ll += __shfl_down(ll, off);
        lc += __shfl_down(lc, off);
    }
    if (lane == 0) {
        if (ll != 0.0f) atomicAdd(&acc[0], ll);
        if (lc != 0.0f) atomicAdd(&acc[1], lc);
    }
}

// ---------------- k_tail: per-batch top-K sum + last-block finalize ----------
// K-th largest via binary search on float bit patterns (values >= 0);
// sum(topK) = sum(v > vK) + (K - cnt_gt)*vK -- exact, tie-order invariant.
__global__ __launch_bounds__(256) void k_tail(
    const float* __restrict__ ce_mined,   // [B*D] (from k_main, prior dispatch)
    const int*   __restrict__ num_pos,    // [B]
    float* __restrict__ acc,              // [2]
    int*   __restrict__ done,             // [1]  (pre-zeroed)
    float* __restrict__ out)              // [2]
{
    const int b   = blockIdx.x;
    const int tid = threadIdx.x;
    const int K   = min(3 * num_pos[b], DD);
    __shared__ int   s_cnt;
    __shared__ float s_sum;

    const float* rowm = ce_mined + (size_t)b * DD;
    unsigned vv[35];                      // 35*256 = 8960 >= 8732
    #pragma unroll
    for (int j = 0; j < 35; j++) {
        int i = tid + j * 256;
        vv[j] = (i < DD) ? __float_as_uint(rowm[i]) : 0u;
    }

    if (K > 0) {                          // uniform per block
        unsigned lo = 0u, hi = 0x7F800000u;
        while (lo < hi) {
            unsigned mid = lo + ((hi - lo) >> 1);
            int c = 0;
            #pragma unroll
            for (int j = 0; j < 35; j++) c += (vv[j] > mid) ? 1 : 0;
            for (int off = 32; off > 0; off >>= 1) c += __shfl_down(c, off);
            if (tid == 0) s_cnt = 0;
            __syncthreads();
            if ((tid & 63) == 0) atomicAdd(&s_cnt, c);
            __syncthreads();
            if (s_cnt >= K) lo = mid + 1; else hi = mid;
            __syncthreads();
        }
        const unsigned ustar = lo;
        const float thr = __uint_as_float(ustar);
        float sum = 0.0f; int cgt = 0;
        #pragma unroll
        for (int j = 0; j < 35; j++) {
            if (vv[j] > ustar) { sum += __uint_as_float(vv[j]); cgt++; }
        }
        for (int off = 32; off > 0; off >>= 1) {
            sum += __shfl_down(sum, off);
            cgt += __shfl_down(cgt, off);
        }
        if (tid == 0) { s_sum = 0.0f; s_cnt = 0; }
        __syncthreads();
        if ((tid & 63) == 0) { atomicAdd(&s_sum, sum); atomicAdd(&s_cnt, cgt); }
        __syncthreads();
        if (tid == 0) atomicAdd(&acc[1], s_sum + (float)(K - s_cnt) * thr);
    }
    __syncthreads();

    if (tid == 0) {
        __threadfence();                       // my acc[1] add visible before done++
        int old = atomicAdd(done, 1);          // device-scope
        if (old == BB - 1) {                   // last block: all adds complete
            __threadfence();
            int np = 0;
            for (int i = 0; i < BB; i++) np += num_pos[i];  // k_main output: safe
            float l0 = acc[0];                              // k_main output: safe
            float l1 = atomicAdd(&acc[1], 0.0f);            // atomic read (RMW)
            float Nt = (float)np;
            out[0] = l0 / Nt;
            out[1] = l1 / Nt;
        }
    }
}

extern "C" void kernel_launch(void* const* d_in, const int* in_sizes, int n_in,
                              void* d_out, int out_size, void* d_ws, size_t ws_size,
                              hipStream_t stream) {
    const float* loc_data  = (const float*)d_in[0];  // [64,8732,4]
    const float* conf_data = (const float*)d_in[1];  // [64,8732,81]
    const float* dboxes    = (const float*)d_in[2];  // [8732,4]
    const float* tboxes    = (const float*)d_in[3];  // [64,50,4]
    const int*   tlabels   = (const int*)d_in[4];    // [64,50]
    float* out = (float*)d_out;

    // ws: ce_mined[B*D] | num_pos[64] | acc[2] | done[1]
    float* ce_mined = (float*)d_ws;
    int*   num_pos  = (int*)(ce_mined + (size_t)BB * DD);
    float* acc      = (float*)(num_pos + BB);
    int*   done     = (int*)(acc + 2);

    hipMemsetAsync(num_pos, 0, (BB + 3) * sizeof(int), stream);  // np + acc + done

    hipLaunchKernelGGL(k_main, dim3(GRID_MAIN), dim3(256), 0, stream,
                       loc_data, conf_data, dboxes, tboxes, tlabels,
                       ce_mined, num_pos, acc);
    hipLaunchKernelGGL(k_tail, dim3(BB), dim3(256), 0, stream,
                       ce_mined, num_pos, acc, done, out);
}

// Round 7
// 485.029 us; speedup vs baseline: 1.6634x; 1.6634x over previous
//
#include <hip/hip_runtime.h>
#include <math.h>

#define BB 64
#define DD 8732
#define CC 81
#define NN 50
#define CE_GRID 2048
#define CE_WAVES (CE_GRID * 4)      // 8192 waves
#define NGROUPS (BB * DD / 4)       // 139712 groups of 4 rows

// conf rows are 324 B apart -> per-row float4 slices are only dword-aligned.
typedef float f4u __attribute__((ext_vector_type(4), aligned(4)));

// ---------------- k_match: per-prior best-IoU gt, conf_t, smooth-L1 ----------
__global__ __launch_bounds__(256) void k_match(
    const float* __restrict__ loc_data,   // [B,D,4]
    const float* __restrict__ dboxes,     // [D,4]
    const float* __restrict__ tboxes,     // [B,N,4]
    const int*   __restrict__ tlabels,    // [B,N]
    unsigned char* __restrict__ conf_t,   // [B,D]
    int* __restrict__ num_pos,            // [B]  (pre-zeroed)
    float* __restrict__ acc)              // [0]=loss_l, [1]=loss_c (pre-zeroed)
{
    __shared__ float s_tb[NN * 4];
    __shared__ float s_area[NN];
    __shared__ int   s_tl[NN];
    const int b   = blockIdx.y;
    const int tid = threadIdx.x;
    const int d   = blockIdx.x * 256 + tid;

    if (tid < NN * 4) s_tb[tid] = tboxes[b * NN * 4 + tid];
    if (tid < NN)     s_tl[tid] = tlabels[b * NN + tid];
    __syncthreads();
    if (tid < NN) {
        float x1 = s_tb[tid*4+0], y1 = s_tb[tid*4+1];
        float x2 = s_tb[tid*4+2], y2 = s_tb[tid*4+3];
        s_area[tid] = (x1 - x2) * (y1 - y2);   // matches reference _area
    }
    __syncthreads();

    const bool active = (d < DD);
    float ll = 0.0f;
    bool pos = false;
    if (active) {
        const float4 db = ((const float4*)dboxes)[d];
        const float dx1 = db.x, dy1 = db.y, dx2 = db.z, dy2 = db.w;
        const float dArea = (dx1 - dx2) * (dy1 - dy2);
        float bestIoU = -1.0f;
        int   bestN = 0;
        for (int n = 0; n < NN; n++) {
            float tx1 = s_tb[n*4+0], ty1 = s_tb[n*4+1];
            float tx2 = s_tb[n*4+2], ty2 = s_tb[n*4+3];
            float lx = fmaxf(tx1, dx1), ly = fmaxf(ty1, dy1);
            float rx = fminf(tx2, dx2), ry = fminf(ty2, dy2);
            float w = fmaxf(rx - lx, 0.0f), h = fmaxf(ry - ly, 0.0f);
            float inter = w * h;
            float iou = inter / (s_area[n] + dArea - inter);
            if (iou > bestIoU) { bestIoU = iou; bestN = n; }  // first-max = jnp.argmax
        }
        int ct = 0;
        if (!(bestIoU < 0.5f)) ct = s_tl[bestN] + 1;
        conf_t[(size_t)b * DD + d] = (unsigned char)ct;
        pos = (ct > 0);
        if (pos) {
            float bx1 = s_tb[bestN*4+0], by1 = s_tb[bestN*4+1];
            float bx2 = s_tb[bestN*4+2], by2 = s_tb[bestN*4+3];
            float dw = dx2 - dx1, dh = dy2 - dy1;
            float t0 = ((bx1 - dx1) + (bx2 - dx2)) * 0.5f * 10.0f / dw;
            float t1 = ((by1 - dy1) + (by2 - dy2)) * 0.5f * 10.0f / dh;
            float t2 = __logf((bx2 - bx1) / dw) * 5.0f;
            float t3 = __logf((by2 - by1) / dh) * 5.0f;
            const float4 ld = ((const float4*)loc_data)[(size_t)b * DD + d];
            float xs[4] = {ld.x - t0, ld.y - t1, ld.z - t2, ld.w - t3};
            #pragma unroll
            for (int k = 0; k < 4; k++) {
                float ax = fabsf(xs[k]);
                ll += (ax < 1.0f) ? 0.5f * xs[k] * xs[k] : ax - 0.5f;
            }
        }
    }
    for (int off = 32; off > 0; off >>= 1) ll += __shfl_down(ll, off);
    unsigned long long bal = __ballot(pos);
    if ((tid & 63) == 0) {
        if (ll != 0.0f) atomicAdd(&acc[0], ll);
        int c = (int)__popcll(bal);
        if (c) atomicAdd(&num_pos[b], c);
    }
}

// ---------------- k_ce: quarter-wave rows, named-register double-buffer ------
// Group = 4 rows; quarter q owns row 4g+q. Lane s: cols 4s..4s+3 (x4),
// s<4: cols 64+4s..67+4s (y4), s==4: col 80 (z). Two named banks (A/B) keep
// the next group's 3 loads in flight while the current group's exp/shfl chain
// runs. No arrays -> no scratch spill.
#define CE_LOAD(X4, Y4, Z, CT, G) do {                                   \
    const int _r = (G) * 4 + q;                                          \
    const float* _row = conf_data + (size_t)_r * CC;                     \
    X4 = *(const f4u*)(_row + 4 * s);                                    \
    if (s < 4)  Y4 = *(const f4u*)(_row + 64 + 4 * s);                   \
    if (s == 4) Z  = _row[80];                                           \
    CT = conf_t[_r];                                                     \
} while (0)

#define CE_COMPUTE(X4, Y4, Z, CT, G) do {                                \
    float _e = __expf(X4.x) + __expf(X4.y) + __expf(X4.z) + __expf(X4.w);\
    if (s < 4)  _e += __expf(Y4.x) + __expf(Y4.y) + __expf(Y4.z) + __expf(Y4.w); \
    if (s == 4) _e += __expf(Z);                                         \
    float _v = 0.f;                                                      \
    const int _ct = CT;                                                  \
    if (_ct < 64) {                                                      \
        if (s == (_ct >> 2)) {                                           \
            int _e3 = _ct & 3;                                           \
            _v = (_e3 == 0) ? X4.x : (_e3 == 1) ? X4.y : (_e3 == 2) ? X4.z : X4.w; \
        }                                                                \
    } else if (_ct < 80) {                                               \
        if (s == ((_ct - 64) >> 2)) {                                    \
            int _e3 = (_ct - 64) & 3;                                    \
            _v = (_e3 == 0) ? Y4.x : (_e3 == 1) ? Y4.y : (_e3 == 2) ? Y4.z : Y4.w; \
        }                                                                \
    } else {                                                             \
        if (s == 4) _v = Z;                                              \
    }                                                                    \
    _Pragma("unroll")                                                    \
    for (int _off = 1; _off < 16; _off <<= 1) {                          \
        _e += __shfl_xor(_e, _off);                                      \
        _v += __shfl_xor(_v, _off);                                      \
    }                                                                    \
    if (s == 0) {                                                        \
        float _ce = fmaxf(__logf(_e) - _v, 0.0f);                        \
        const int _r = (G) * 4 + q;                                      \
        bool _pos = (_ct > 0);                                           \
        ce_mined[_r] = _pos ? 0.0f : _ce;                                \
        if (_pos) lc += _ce;                                             \
    }                                                                    \
} while (0)

__global__ __launch_bounds__(256) void k_ce(
    const float* __restrict__ conf_data,      // [B,D,C]
    const unsigned char* __restrict__ conf_t, // [B,D]
    float* __restrict__ ce_mined,             // [B*D] (positives zeroed)
    float* __restrict__ acc)
{
    const int tid  = threadIdx.x;
    const int lane = tid & 63;
    const int q    = lane >> 4;
    const int s    = lane & 15;
    const int gw   = (blockIdx.x * 256 + tid) >> 6;

    float lc = 0.0f;
    f4u ax4, ay4 = {0,0,0,0};  float az = 0.f;  int act = 0;
    f4u bx4, by4 = {0,0,0,0};  float bz = 0.f;  int bct = 0;

    int g = gw;
    if (g < NGROUPS) CE_LOAD(ax4, ay4, az, act, g);
    while (g < NGROUPS) {
        int gn = g + CE_WAVES;                       // wave-uniform
        if (gn < NGROUPS) CE_LOAD(bx4, by4, bz, bct, gn);
        CE_COMPUTE(ax4, ay4, az, act, g);
        g = gn;
        if (g >= NGROUPS) break;
        gn = g + CE_WAVES;
        if (gn < NGROUPS) CE_LOAD(ax4, ay4, az, act, gn);
        CE_COMPUTE(bx4, by4, bz, bct, g);
        g = gn;
    }

    #pragma unroll
    for (int off = 32; off > 0; off >>= 1) lc += __shfl_down(lc, off);
    if (lane == 0 && lc != 0.0f) atomicAdd(&acc[1], lc);
}

// ---------------- k_tail: per-batch top-K sum + last-block finalize ----------
__global__ __launch_bounds__(256) void k_tail(
    const float* __restrict__ ce_mined,   // [B*D]
    const int*   __restrict__ num_pos,    // [B]
    float* __restrict__ acc,              // [2]
    int*   __restrict__ done,             // [1]  (pre-zeroed)
    float* __restrict__ out)              // [2]
{
    const int b   = blockIdx.x;
    const int tid = threadIdx.x;
    const int K   = min(3 * num_pos[b], DD);
    __shared__ int   s_cnt;
    __shared__ float s_sum;

    const float* rowm = ce_mined + (size_t)b * DD;
    unsigned vv[35];                      // 35*256 = 8960 >= 8732
    #pragma unroll
    for (int j = 0; j < 35; j++) {
        int i = tid + j * 256;
        vv[j] = (i < DD) ? __float_as_uint(rowm[i]) : 0u;
    }

    if (K > 0) {                          // uniform per block
        unsigned lo = 0u, hi = 0x7F800000u;
        while (lo < hi) {
            unsigned mid = lo + ((hi - lo) >> 1);
            int c = 0;
            #pragma unroll
            for (int j = 0; j < 35; j++) c += (vv[j] > mid) ? 1 : 0;
            for (int off = 32; off > 0; off >>= 1) c += __shfl_down(c, off);
            if (tid == 0) s_cnt = 0;
            __syncthreads();
            if ((tid & 63) == 0) atomicAdd(&s_cnt, c);
            __syncthreads();
            if (s_cnt >= K) lo = mid + 1; else hi = mid;
            __syncthreads();
        }
        const unsigned ustar = lo;
        const float thr = __uint_as_float(ustar);
        float sum = 0.0f; int cgt = 0;
        #pragma unroll
        for (int j = 0; j < 35; j++) {
            if (vv[j] > ustar) { sum += __uint_as_float(vv[j]); cgt++; }
        }
        for (int off = 32; off > 0; off >>= 1) {
            sum += __shfl_down(sum, off);
            cgt += __shfl_down(cgt, off);
        }
        if (tid == 0) { s_sum = 0.0f; s_cnt = 0; }
        __syncthreads();
        if ((tid & 63) == 0) { atomicAdd(&s_sum, sum); atomicAdd(&s_cnt, cgt); }
        __syncthreads();
        if (tid == 0) atomicAdd(&acc[1], s_sum + (float)(K - s_cnt) * thr);
    }
    __syncthreads();

    if (tid == 0) {
        __threadfence();                       // my acc[1] add visible before done++
        int old = atomicAdd(done, 1);          // device-scope
        if (old == BB - 1) {                   // last block: all adds complete
            __threadfence();
            int np = 0;
            for (int i = 0; i < BB; i++) np += num_pos[i];
            float l0 = acc[0];
            float l1 = atomicAdd(&acc[1], 0.0f);            // atomic read (RMW)
            float Nt = (float)np;
            out[0] = l0 / Nt;
            out[1] = l1 / Nt;
        }
    }
}

extern "C" void kernel_launch(void* const* d_in, const int* in_sizes, int n_in,
                              void* d_out, int out_size, void* d_ws, size_t ws_size,
                              hipStream_t stream) {
    const float* loc_data  = (const float*)d_in[0];  // [64,8732,4]
    const float* conf_data = (const float*)d_in[1];  // [64,8732,81]
    const float* dboxes    = (const float*)d_in[2];  // [8732,4]
    const float* tboxes    = (const float*)d_in[3];  // [64,50,4]
    const int*   tlabels   = (const int*)d_in[4];    // [64,50]
    float* out = (float*)d_out;

    // ws: ce_mined[B*D] | conf_t[B*D] | num_pos[64] | acc[2] | done[1]
    float*         ce_mined = (float*)d_ws;
    unsigned char* conf_t   = (unsigned char*)(ce_mined + (size_t)BB * DD);
    int*           num_pos  = (int*)(conf_t + (size_t)BB * DD);   // B*D % 4 == 0
    float*         acc      = (float*)(num_pos + BB);
    int*           done     = (int*)(acc + 2);

    hipMemsetAsync(num_pos, 0, (BB + 3) * sizeof(int), stream);  // np + acc + done

    hipLaunchKernelGGL(k_match, dim3((DD + 255) / 256, BB), dim3(256), 0, stream,
                       loc_data, dboxes, tboxes, tlabels, conf_t, num_pos, acc);
    hipLaunchKernelGGL(k_ce, dim3(CE_GRID), dim3(256), 0, stream,
                       conf_data, conf_t, ce_mined, acc);
    hipLaunchKernelGGL(k_tail, dim3(BB), dim3(256), 0, stream,
                       ce_mined, num_pos, acc, done, out);
}

// Round 8
// 452.336 us; speedup vs baseline: 1.7837x; 1.0723x over previous
//
#include <hip/hip_runtime.h>
#include <math.h>

#define BB 64
#define DD 8732
#define CC 81
#define NN 50
#define TROWS 64                    // rows per tile
#define TFL4  1296                  // 64*81/4 float4 per tile (20736 B)
#define CE_GRID 1024                // 4 blocks/CU
#define NTILES (BB * DD / TROWS)    // 8732 exactly

// ---------------- k_match: per-prior best-IoU gt, conf_t, smooth-L1 ----------
__global__ __launch_bounds__(256) void k_match(
    const float* __restrict__ loc_data,   // [B,D,4]
    const float* __restrict__ dboxes,     // [D,4]
    const float* __restrict__ tboxes,     // [B,N,4]
    const int*   __restrict__ tlabels,    // [B,N]
    unsigned char* __restrict__ conf_t,   // [B,D]
    int* __restrict__ num_pos,            // [B]  (pre-zeroed)
    float* __restrict__ acc)              // [0]=loss_l, [1]=loss_c (pre-zeroed)
{
    __shared__ float s_tb[NN * 4];
    __shared__ float s_area[NN];
    __shared__ int   s_tl[NN];
    const int b   = blockIdx.y;
    const int tid = threadIdx.x;
    const int d   = blockIdx.x * 256 + tid;

    if (tid < NN * 4) s_tb[tid] = tboxes[b * NN * 4 + tid];
    if (tid < NN)     s_tl[tid] = tlabels[b * NN + tid];
    __syncthreads();
    if (tid < NN) {
        float x1 = s_tb[tid*4+0], y1 = s_tb[tid*4+1];
        float x2 = s_tb[tid*4+2], y2 = s_tb[tid*4+3];
        s_area[tid] = (x1 - x2) * (y1 - y2);   // matches reference _area
    }
    __syncthreads();

    const bool active = (d < DD);
    float ll = 0.0f;
    bool pos = false;
    if (active) {
        const float4 db = ((const float4*)dboxes)[d];
        const float dx1 = db.x, dy1 = db.y, dx2 = db.z, dy2 = db.w;
        const float dArea = (dx1 - dx2) * (dy1 - dy2);
        float bestIoU = -1.0f;
        int   bestN = 0;
        for (int n = 0; n < NN; n++) {
            float tx1 = s_tb[n*4+0], ty1 = s_tb[n*4+1];
            float tx2 = s_tb[n*4+2], ty2 = s_tb[n*4+3];
            float lx = fmaxf(tx1, dx1), ly = fmaxf(ty1, dy1);
            float rx = fminf(tx2, dx2), ry = fminf(ty2, dy2);
            float w = fmaxf(rx - lx, 0.0f), h = fmaxf(ry - ly, 0.0f);
            float inter = w * h;
            float iou = inter / (s_area[n] + dArea - inter);
            if (iou > bestIoU) { bestIoU = iou; bestN = n; }  // first-max = jnp.argmax
        }
        int ct = 0;
        if (!(bestIoU < 0.5f)) ct = s_tl[bestN] + 1;
        conf_t[(size_t)b * DD + d] = (unsigned char)ct;
        pos = (ct > 0);
        if (pos) {
            float bx1 = s_tb[bestN*4+0], by1 = s_tb[bestN*4+1];
            float bx2 = s_tb[bestN*4+2], by2 = s_tb[bestN*4+3];
            float dw = dx2 - dx1, dh = dy2 - dy1;
            float t0 = ((bx1 - dx1) + (bx2 - dx2)) * 0.5f * 10.0f / dw;
            float t1 = ((by1 - dy1) + (by2 - dy2)) * 0.5f * 10.0f / dh;
            float t2 = __logf((bx2 - bx1) / dw) * 5.0f;
            float t3 = __logf((by2 - by1) / dh) * 5.0f;
            const float4 ld = ((const float4*)loc_data)[(size_t)b * DD + d];
            float xs[4] = {ld.x - t0, ld.y - t1, ld.z - t2, ld.w - t3};
            #pragma unroll
            for (int k = 0; k < 4; k++) {
                float ax = fabsf(xs[k]);
                ll += (ax < 1.0f) ? 0.5f * xs[k] * xs[k] : ax - 0.5f;
            }
        }
    }
    for (int off = 32; off > 0; off >>= 1) ll += __shfl_down(ll, off);
    unsigned long long bal = __ballot(pos);
    if ((tid & 63) == 0) {
        if (ll != 0.0f) atomicAdd(&acc[0], ll);
        int c = (int)__popcll(bal);
        if (c) atomicAdd(&num_pos[b], c);
    }
}

// ---------------- k_ce: LDS tile staging, named-reg prefetch (no arrays) -----
// Tile = 64 rows (20736 B). LOAD issues 6 wide coalesced float4 reads into
// NAMED registers r0..r5; they are stored to LDS at the top of the next
// iteration, so the global loads stay in flight across the compute phase.
__global__ __launch_bounds__(256) void k_ce(
    const float* __restrict__ conf_data,      // [B,D,C]
    const unsigned char* __restrict__ conf_t, // [B,D]
    float* __restrict__ ce_mined,             // [B*D] (positives zeroed)
    float* __restrict__ acc)
{
    __shared__ float4 sbuf[TFL4];             // 20736 B
    const int tid  = threadIdx.x;
    const int lane = tid & 63;
    const int w    = tid >> 6;        // wave in block (0..3)
    const int q    = lane >> 4;       // quarter (0..3)
    const int s    = lane & 15;       // sublane within quarter

    float4 r0, r1, r2, r3, r4, r5;
    float lc = 0.0f;

    int t = blockIdx.x;
    {
        const float4* src = (const float4*)conf_data + (size_t)t * TFL4;
        r0 = src[tid];
        r1 = src[tid + 256];
        r2 = src[tid + 512];
        r3 = src[tid + 768];
        r4 = src[tid + 1024];
        if (tid < 16) r5 = src[1280 + tid];
    }
    for (; t < NTILES; t += CE_GRID) {
        __syncthreads();                      // prior compute done; LDS reusable
        sbuf[tid]        = r0;                // vmcnt wait lands here
        sbuf[tid + 256]  = r1;
        sbuf[tid + 512]  = r2;
        sbuf[tid + 768]  = r3;
        sbuf[tid + 1024] = r4;
        if (tid < 16) sbuf[1280 + tid] = r5;
        const int tn = t + CE_GRID;
        if (tn < NTILES) {                    // issue next tile's loads NOW
            const float4* src = (const float4*)conf_data + (size_t)tn * TFL4;
            r0 = src[tid];
            r1 = src[tid + 256];
            r2 = src[tid + 512];
            r3 = src[tid + 768];
            r4 = src[tid + 1024];
            if (tid < 16) r5 = src[1280 + tid];
        }
        __syncthreads();                      // tile t visible in LDS

        const float* sb = (const float*)sbuf;
        #pragma unroll
        for (int i = 0; i < 4; i++) {
            const int lr = w * 16 + i * 4 + q;        // local row 0..63
            const float* row = sb + lr * CC;
            float x0 = row[s];
            float x1 = row[s + 16];
            float x2 = row[s + 32];
            float x3 = row[s + 48];
            float x4 = row[s + 64];
            float x5 = (s == 0) ? row[80] : 0.0f;
            const int r = t * TROWS + lr;
            const int ct = conf_t[r];

            float e = __expf(x0) + __expf(x1) + __expf(x2) + __expf(x3) + __expf(x4);
            if (s == 0) e += __expf(x5);

            const int k  = ct >> 4;
            const int sl = ct & 15;
            float xv = (k == 0) ? x0 : (k == 1) ? x1 : (k == 2) ? x2
                     : (k == 3) ? x3 : (k == 4) ? x4 : x5;
            float v = (s == sl) ? xv : 0.0f;

            #pragma unroll
            for (int off = 1; off < 16; off <<= 1) {
                e += __shfl_xor(e, off);
                v += __shfl_xor(v, off);
            }
            if (s == 0) {
                float ce = fmaxf(__logf(e) - v, 0.0f);
                bool pos = (ct > 0);
                ce_mined[r] = pos ? 0.0f : ce;
                if (pos) lc += ce;
            }
        }
    }
    #pragma unroll
    for (int off = 32; off > 0; off >>= 1) lc += __shfl_down(lc, off);
    if (lane == 0 && lc != 0.0f) atomicAdd(&acc[1], lc);
}

// ---------------- k_tail: per-batch top-K sum + last-block finalize ----------
// K-th largest via binary search on float bit patterns (values >= 0);
// sum(topK) = sum(v > vK) + (K - cnt_gt)*vK -- exact, tie-order invariant.
__global__ __launch_bounds__(256) void k_tail(
    const float* __restrict__ ce_mined,   // [B*D]
    const int*   __restrict__ num_pos,    // [B]
    float* __restrict__ acc,              // [2]
    int*   __restrict__ done,             // [1]  (pre-zeroed)
    float* __restrict__ out)              // [2]
{
    const int b   = blockIdx.x;
    const int tid = threadIdx.x;
    const int K   = min(3 * num_pos[b], DD);
    __shared__ int   s_cnt;
    __shared__ float s_sum;

    const float* rowm = ce_mined + (size_t)b * DD;
    unsigned vv[35];                      // 35*256 = 8960 >= 8732
    #pragma unroll
    for (int j = 0; j < 35; j++) {
        int i = tid + j * 256;
        vv[j] = (i < DD) ? __float_as_uint(rowm[i]) : 0u;
    }

    if (K > 0) {                          // uniform per block
        unsigned lo = 0u, hi = 0x7F800000u;
        while (lo < hi) {
            unsigned mid = lo + ((hi - lo) >> 1);
            int c = 0;
            #pragma unroll
            for (int j = 0; j < 35; j++) c += (vv[j] > mid) ? 1 : 0;
            for (int off = 32; off > 0; off >>= 1) c += __shfl_down(c, off);
            if (tid == 0) s_cnt = 0;
            __syncthreads();
            if ((tid & 63) == 0) atomicAdd(&s_cnt, c);
            __syncthreads();
            if (s_cnt >= K) lo = mid + 1; else hi = mid;
            __syncthreads();
        }
        const unsigned ustar = lo;
        const float thr = __uint_as_float(ustar);
        float sum = 0.0f; int cgt = 0;
        #pragma unroll
        for (int j = 0; j < 35; j++) {
            if (vv[j] > ustar) { sum += __uint_as_float(vv[j]); cgt++; }
        }
        for (int off = 32; off > 0; off >>= 1) {
            sum += __shfl_down(sum, off);
            cgt += __shfl_down(cgt, off);
        }
        if (tid == 0) { s_sum = 0.0f; s_cnt = 0; }
        __syncthreads();
        if ((tid & 63) == 0) { atomicAdd(&s_sum, sum); atomicAdd(&s_cnt, cgt); }
        __syncthreads();
        if (tid == 0) atomicAdd(&acc[1], s_sum + (float)(K - s_cnt) * thr);
    }
    __syncthreads();

    if (tid == 0) {
        __threadfence();                       // my acc[1] add visible before done++
        int old = atomicAdd(done, 1);          // device-scope
        if (old == BB - 1) {                   // last block: all adds complete
            __threadfence();
            int np = 0;
            for (int i = 0; i < BB; i++) np += num_pos[i];
            float l0 = acc[0];
            float l1 = atomicAdd(&acc[1], 0.0f);            // atomic read (RMW)
            float Nt = (float)np;
            out[0] = l0 / Nt;
            out[1] = l1 / Nt;
        }
    }
}

extern "C" void kernel_launch(void* const* d_in, const int* in_sizes, int n_in,
                              void* d_out, int out_size, void* d_ws, size_t ws_size,
                              hipStream_t stream) {
    const float* loc_data  = (const float*)d_in[0];  // [64,8732,4]
    const float* conf_data = (const float*)d_in[1];  // [64,8732,81]
    const float* dboxes    = (const float*)d_in[2];  // [8732,4]
    const float* tboxes    = (const float*)d_in[3];  // [64,50,4]
    const int*   tlabels   = (const int*)d_in[4];    // [64,50]
    float* out = (float*)d_out;

    // ws: ce_mined[B*D] | conf_t[B*D] | num_pos[64] | acc[2] | done[1]
    float*         ce_mined = (float*)d_ws;
    unsigned char* conf_t   = (unsigned char*)(ce_mined + (size_t)BB * DD);
    int*           num_pos  = (int*)(conf_t + (size_t)BB * DD);   // B*D % 4 == 0
    float*         acc      = (float*)(num_pos + BB);
    int*           done     = (int*)(acc + 2);

    hipMemsetAsync(num_pos, 0, (BB + 3) * sizeof(int), stream);  // np + acc + done

    hipLaunchKernelGGL(k_match, dim3((DD + 255) / 256, BB), dim3(256), 0, stream,
                       loc_data, dboxes, tboxes, tlabels, conf_t, num_pos, acc);
    hipLaunchKernelGGL(k_ce, dim3(CE_GRID), dim3(256), 0, stream,
                       conf_data, conf_t, ce_mined, acc);
    hipLaunchKernelGGL(k_tail, dim3(BB), dim3(256), 0, stream,
                       ce_mined, num_pos, acc, done, out);
}